// Round 2
// baseline (1619.233 us; speedup 1.0000x reference)
//
#include <hip/hip_runtime.h>
#include <stdint.h>

#define B_ 2
#define S_ 2048
#define E_ 4096
#define H_ 32
#define KVH_ 8
#define D_ 128

typedef __bf16 bf16_t;
typedef __bf16 bf16x8 __attribute__((ext_vector_type(8)));
typedef __bf16 bf16x4 __attribute__((ext_vector_type(4)));
typedef float f32x4 __attribute__((ext_vector_type(4)));

// global -> LDS direct copy, 16B per lane. LDS dest = wave-uniform base + lane*16.
__device__ __forceinline__ void gl2lds16(const void* g, void* l) {
  __builtin_amdgcn_global_load_lds(
      (__attribute__((address_space(1))) void*)(uintptr_t)g,
      (__attribute__((address_space(3))) void*)(uint32_t)(uintptr_t)l,
      16, 0, 0);
}

// ---------------- elementwise fp32 -> bf16 ----------------
__global__ void cvt_f32_bf16(const float* __restrict__ in, bf16_t* __restrict__ out, int n4) {
  int i = blockIdx.x * 256 + threadIdx.x;
  if (i < n4) {
    float4 v = ((const float4*)in)[i];
    bf16x4 o;
    o.x = (bf16_t)v.x; o.y = (bf16_t)v.y; o.z = (bf16_t)v.z; o.w = (bf16_t)v.w;
    ((bf16x4*)out)[i] = o;
  }
}

// ---------------- transpose + convert: in (R,C) fp32 -> out (C,R) bf16 ----------------
__global__ void transpose_cvt(const float* __restrict__ in, bf16_t* __restrict__ out,
                              int R, int C) {
  __shared__ float t[32][33];
  int r0 = blockIdx.y * 32, c0 = blockIdx.x * 32;
  int tx = threadIdx.x & 31, tg = threadIdx.x >> 5;
#pragma unroll
  for (int k = 0; k < 4; ++k) {
    int r = tg * 4 + k;
    t[r][tx] = in[(long)(r0 + r) * C + c0 + tx];
  }
  __syncthreads();
#pragma unroll
  for (int k = 0; k < 4; ++k) {
    int r = tg * 4 + k;
    out[(long)(c0 + r) * R + r0 + tx] = (bf16_t)t[tx][r];
  }
}

// ---------------- V: (B*S, KVH*D) fp32 -> (B,KVH,D,S) bf16 ----------------
__global__ void transpose_v(const float* __restrict__ Vtmp, bf16_t* __restrict__ Vt) {
  __shared__ float t[32][33];
  int z = blockIdx.z, b = z >> 3, kv = z & 7;
  const float* in = Vtmp + (long)b * S_ * (KVH_ * D_) + kv * D_;
  bf16_t* out = Vt + ((long)(b * KVH_ + kv)) * D_ * S_;
  int s0 = blockIdx.y * 32, d0 = blockIdx.x * 32;
  int tx = threadIdx.x & 31, tg = threadIdx.x >> 5;
#pragma unroll
  for (int k = 0; k < 4; ++k) {
    int r = tg * 4 + k;
    t[r][tx] = in[(long)(s0 + r) * (KVH_ * D_) + d0 + tx];
  }
  __syncthreads();
#pragma unroll
  for (int k = 0; k < 4; ++k) {
    int r = tg * 4 + k;
    out[(long)(d0 + r) * S_ + s0 + tx] = (bf16_t)t[tx][r];
  }
}

// ---------------- RoPE + layout: (B*S, NH*D) fp32 -> (B,NH,S,D) bf16, * scale ----------------
__global__ void rope_cvt(const float* __restrict__ T, bf16_t* __restrict__ out,
                         const int* __restrict__ pos, int NH, float scale) {
  long idx = (long)blockIdx.x * 256 + threadIdx.x;  // B*NH*S*64 total
  int j = (int)(idx & 63);
  long t = idx >> 6;
  int s = (int)(t % S_); t /= S_;
  int nh = (int)(t % NH);
  int b = (int)(t / NH);
  long row = ((long)b * S_ + s) * ((long)NH * D_) + (long)nh * D_;
  float x1 = T[row + j];
  float x2 = T[row + j + 64];
  float p = (float)pos[(long)b * S_ + s];
  float inv = expf(-(float)j * (9.210340371976184f / 64.0f));  // 10000^(-j/64)
  float fr = p * inv;
  float c = cosf(fr), sn = sinf(fr);
  long ob = (((long)b * NH + nh) * S_ + s) * D_;
  out[ob + j]      = (bf16_t)((x1 * c - x2 * sn) * scale);
  out[ob + j + 64] = (bf16_t)((x2 * c + x1 * sn) * scale);
}

// ---------------- GEMM: C(M,N) fp32 = A(M,K) bf16 * Bt(N,K)^T bf16 ----------------
// m97 structure + XOR-swizzled LDS (granule g -> g ^ (row&7), 16B granules, 8/row).
__global__ __launch_bounds__(256, 2) void gemm_bt(
    const bf16_t* __restrict__ A, const bf16_t* __restrict__ Bt,
    float* __restrict__ C, int M, int N, int K) {
  __shared__ bf16_t As[128 * 64];
  __shared__ bf16_t Bs[128 * 64];
  const int tid = threadIdx.x;
  const int lane = tid & 63;
  const int wave = tid >> 6;
  const int m0 = blockIdx.y * 128, n0 = blockIdx.x * 128;
  const int wm = (wave >> 1) * 64, wn = (wave & 1) * 64;
  const int ln = lane & 15, quad = lane >> 4;
  const int srow = lane >> 3;          // row within 8-row chunk
  const int sg = lane & 7;             // granule slot within row

  f32x4 acc[4][4] = {};

  for (int kb = 0; kb < K; kb += 64) {
    __syncthreads();
#pragma unroll
    for (int it = 0; it < 4; ++it) {
      int c = wave * 4 + it;
      int row = c * 8 + srow;
      int g = sg ^ (row & 7);          // source granule for swizzled slot sg
      gl2lds16(A + (long)(m0 + row) * K + kb + g * 8, &As[c * 512 + lane * 8]);
      gl2lds16(Bt + (long)(n0 + row) * K + kb + g * 8, &Bs[c * 512 + lane * 8]);
    }
    __syncthreads();
#pragma unroll
    for (int ks = 0; ks < 2; ++ks) {
      bf16x8 af[4], bfr[4];
      const int go = ((ks * 4 + quad) ^ (ln & 7)) * 8;
#pragma unroll
      for (int i = 0; i < 4; ++i)
        af[i] = *(const bf16x8*)&As[(wm + i * 16 + ln) * 64 + go];
#pragma unroll
      for (int j = 0; j < 4; ++j)
        bfr[j] = *(const bf16x8*)&Bs[(wn + j * 16 + ln) * 64 + go];
#pragma unroll
      for (int i = 0; i < 4; ++i)
#pragma unroll
        for (int j = 0; j < 4; ++j)
          acc[i][j] = __builtin_amdgcn_mfma_f32_16x16x32_bf16(af[i], bfr[j], acc[i][j], 0, 0, 0);
    }
  }
#pragma unroll
  for (int i = 0; i < 4; ++i)
#pragma unroll
    for (int j = 0; j < 4; ++j)
#pragma unroll
      for (int r = 0; r < 4; ++r) {
        int m = m0 + wm + i * 16 + quad * 4 + r;
        int n = n0 + wn + j * 16 + ln;
        C[(long)m * N + n] = acc[i][j][r];
      }
}

// ---------------- causal GQA flash attention ----------------
// Q (B,H,S,D) bf16 PRE-SCALED by log2(e)/sqrt(D), Kr (B,KVH,S,D), Vt (B,KVH,D,S)
// -> X (B*S, H*D) bf16.  LDS: Ks (aliased with per-wave P) + Vs = 64 KB -> 2 blocks/CU.
// All LDS tiles XOR-swizzled: 16 granules of 16B per 256B row, slot = g ^ (row&15).
__global__ __launch_bounds__(256, 2) void flash_attn(
    const bf16_t* __restrict__ Q, const bf16_t* __restrict__ Kr,
    const bf16_t* __restrict__ Vt, bf16_t* __restrict__ X) {
  __shared__ bf16_t Ks[128 * 128];   // QK operand; per-wave P quadrant after barrier C
  __shared__ bf16_t Vs[128 * 128];
  const int tid = threadIdx.x, lane = tid & 63, wave = tid >> 6;
  const int ln = lane & 15, quad = lane >> 4;
  const int qi = (int)(gridDim.x - 1 - blockIdx.x);  // heavy blocks dispatch first
  const int h = blockIdx.y, b = blockIdx.z;
  const int kv = h >> 2;  // GROUPS = 4
  const bf16_t* Kbase = Kr + (((long)b * KVH_ + kv) * S_) * D_;
  const bf16_t* Vbase = Vt + (((long)b * KVH_ + kv) * D_) * S_;
  bf16_t* Pw = &Ks[wave * 4096];     // this wave's 32x128 P tile (rows wave*32..)

  // Q fragments in registers (A-operand layout), Q already scaled
  bf16x8 aq[2][4];
  {
    const bf16_t* Qw = Q + (((long)b * H_ + h) * S_ + qi * 128 + wave * 32) * D_;
#pragma unroll
    for (int i = 0; i < 2; ++i)
#pragma unroll
      for (int ks = 0; ks < 4; ++ks)
        aq[i][ks] = *(const bf16x8*)(Qw + (i * 16 + ln) * D_ + ks * 32 + quad * 8);
  }

  f32x4 o_acc[2][8] = {};
  float m_cur[2][4], l_cur[2][4];
#pragma unroll
  for (int i = 0; i < 2; ++i)
#pragma unroll
    for (int r = 0; r < 4; ++r) { m_cur[i][r] = -__builtin_inff(); l_cur[i][r] = 0.f; }

  for (int jt = 0; jt <= qi; ++jt) {
    __syncthreads();  // (A) prior iter's P/Vs reads done before restaging
    const bf16_t* Kt = Kbase + (long)jt * 128 * D_;
#pragma unroll
    for (int it = 0; it < 8; ++it) {
      int c = wave * 8 + it;
      int row = c * 4 + quad;                 // LDS row (4 rows / 1KB chunk)
      int g = ln ^ (row & 15);                // source granule for slot ln
      gl2lds16(Kt + (long)row * D_ + g * 8, &Ks[c * 512 + lane * 8]);
      gl2lds16(Vbase + (long)row * S_ + jt * 128 + g * 8, &Vs[c * 512 + lane * 8]);
    }
    __syncthreads();  // (B) staging visible

    // S = Q K^T (base-2 log domain; Q pre-scaled)
    f32x4 s_acc[2][8] = {};
#pragma unroll
    for (int ks = 0; ks < 4; ++ks) {
      bf16x8 bk[8];
      const int go = ((ks * 4 + quad) ^ ln) * 8;
#pragma unroll
      for (int j = 0; j < 8; ++j)
        bk[j] = *(const bf16x8*)&Ks[(j * 16 + ln) * 128 + go];
#pragma unroll
      for (int i = 0; i < 2; ++i)
#pragma unroll
        for (int j = 0; j < 8; ++j)
          s_acc[i][j] = __builtin_amdgcn_mfma_f32_16x16x32_bf16(aq[i][ks], bk[j], s_acc[i][j], 0, 0, 0);
    }
    __syncthreads();  // (C) all waves done reading Ks -> safe to write P over it

#pragma unroll
    for (int i = 0; i < 2; ++i) {
      float rmax[4];
#pragma unroll
      for (int r = 0; r < 4; ++r) rmax[r] = -__builtin_inff();
#pragma unroll
      for (int j = 0; j < 8; ++j)
#pragma unroll
        for (int r = 0; r < 4; ++r) {
          float v = s_acc[i][j][r];
          if (jt == qi) {
            int qrow = wave * 32 + i * 16 + quad * 4 + r;
            int kcol = j * 16 + ln;
            if (kcol > qrow) v = -__builtin_inff();
          }
          s_acc[i][j][r] = v;
          rmax[r] = fmaxf(rmax[r], v);
        }
#pragma unroll
      for (int r = 0; r < 4; ++r) {
        float v = rmax[r];
        v = fmaxf(v, __shfl_xor(v, 1));
        v = fmaxf(v, __shfl_xor(v, 2));
        v = fmaxf(v, __shfl_xor(v, 4));
        v = fmaxf(v, __shfl_xor(v, 8));
        rmax[r] = v;
      }
      float alpha[4];
#pragma unroll
      for (int r = 0; r < 4; ++r) {
        float mn = fmaxf(m_cur[i][r], rmax[r]);
        alpha[r] = exp2f(m_cur[i][r] - mn);
        m_cur[i][r] = mn;
      }
      float rsum[4] = {0.f, 0.f, 0.f, 0.f};
#pragma unroll
      for (int j = 0; j < 8; ++j)
#pragma unroll
        for (int r = 0; r < 4; ++r) {
          float p = exp2f(s_acc[i][j][r] - m_cur[i][r]);
          s_acc[i][j][r] = p;
          rsum[r] += p;
        }
#pragma unroll
      for (int r = 0; r < 4; ++r) {
        float v = rsum[r];
        v += __shfl_xor(v, 1);
        v += __shfl_xor(v, 2);
        v += __shfl_xor(v, 4);
        v += __shfl_xor(v, 8);
        l_cur[i][r] = l_cur[i][r] * alpha[r] + v;
      }
#pragma unroll
      for (int j = 0; j < 8; ++j)
#pragma unroll
        for (int r = 0; r < 4; ++r)
          o_acc[i][j][r] *= alpha[r];
      // P -> wave-local LDS quadrant (swizzled), C-layout -> row-major 32x128
#pragma unroll
      for (int j = 0; j < 8; ++j)
#pragma unroll
        for (int r = 0; r < 4; ++r) {
          int prow = i * 16 + quad * 4 + r;
          int pg = (j * 2 + (ln >> 3)) ^ (prow & 15);
          Pw[prow * 128 + pg * 8 + (ln & 7)] = (bf16_t)s_acc[i][j][r];
        }
    }

    // O += P * V
#pragma unroll
    for (int ks = 0; ks < 4; ++ks) {
      bf16x8 ap[2], bv[8];
      const int go = ((ks * 4 + quad) ^ ln) * 8;
#pragma unroll
      for (int i = 0; i < 2; ++i)
        ap[i] = *(const bf16x8*)&Pw[(i * 16 + ln) * 128 + go];
#pragma unroll
      for (int j = 0; j < 8; ++j)
        bv[j] = *(const bf16x8*)&Vs[(j * 16 + ln) * 128 + go];
#pragma unroll
      for (int i = 0; i < 2; ++i)
#pragma unroll
        for (int j = 0; j < 8; ++j)
          o_acc[i][j] = __builtin_amdgcn_mfma_f32_16x16x32_bf16(ap[i], bv[j], o_acc[i][j], 0, 0, 0);
    }
  }

  // epilogue: X[b*S+q][h*D+d] = O / l
#pragma unroll
  for (int i = 0; i < 2; ++i) {
    float rl[4];
#pragma unroll
    for (int r = 0; r < 4; ++r) rl[r] = 1.0f / l_cur[i][r];
#pragma unroll
    for (int j = 0; j < 8; ++j)
#pragma unroll
      for (int r = 0; r < 4; ++r) {
        int q = qi * 128 + wave * 32 + i * 16 + quad * 4 + r;
        int dcol = j * 16 + ln;
        float o = o_acc[i][j][r] * rl[r];
        X[((long)b * S_ + q) * (H_ * D_) + (long)h * D_ + dcol] = (bf16_t)o;
      }
  }
}

extern "C" void kernel_launch(void* const* d_in, const int* in_sizes, int n_in,
                              void* d_out, int out_size, void* d_ws, size_t ws_size,
                              hipStream_t stream) {
  const float* query = (const float*)d_in[0];
  const float* key   = (const float*)d_in[1];
  const float* value = (const float*)d_in[2];
  const int*   pos   = (const int*)d_in[3];
  // d_in[4] = src_mask: deterministic causal tril -> handled analytically
  const float* Wq = (const float*)d_in[5];
  const float* Wk = (const float*)d_in[6];
  const float* Wv = (const float*)d_in[7];
  const float* Wo = (const float*)d_in[8];
  float* out = (float*)d_out;

  char* ws = (char*)d_ws;
  size_t off = 0;
  auto alloc = [&](size_t bytes) {
    char* p = ws + off;
    off += (bytes + 1023) & ~(size_t)1023;
    return p;
  };
  bf16_t* Wqt = (bf16_t*)alloc(33554432);  // (H*D, E) bf16
  bf16_t* Wkt = (bf16_t*)alloc(8388608);   // (KVH*D, E)
  bf16_t* Wvt = (bf16_t*)alloc(8388608);
  bf16_t* Wot = (bf16_t*)alloc(33554432);  // (E, H*D)
  bf16_t* Xq  = (bf16_t*)alloc(33554432);  // query bf16
  bf16_t* Xk  = (bf16_t*)alloc(33554432);
  bf16_t* Xv  = (bf16_t*)alloc(33554432);
  float*  Ktmp = (float*)alloc(16777216);  // (B*S, KVH*D) fp32
  float*  Vtmp = (float*)alloc(16777216);
  float*  Qtmp = out;                      // reuse d_out as fp32 Q-proj scratch
  bf16_t* Qr = Xk;                         // (B,H,S,D)    — Xk dead after K proj
  bf16_t* Kr = Xv;                         // (B,KVH,S,D)  — Xv dead after V proj
  bf16_t* Vt = (bf16_t*)((char*)Xv + 8388608);  // (B,KVH,D,S)
  bf16_t* X  = Xq;                         // attn out — Xq dead after Q proj

  const int n4 = B_ * S_ * E_ / 4;
  cvt_f32_bf16<<<n4 / 256, 256, 0, stream>>>(query, Xq, n4);
  cvt_f32_bf16<<<n4 / 256, 256, 0, stream>>>(key, Xk, n4);
  cvt_f32_bf16<<<n4 / 256, 256, 0, stream>>>(value, Xv, n4);

  transpose_cvt<<<dim3(128, 128), 256, 0, stream>>>(Wq, Wqt, 4096, 4096);
  transpose_cvt<<<dim3(32, 128), 256, 0, stream>>>(Wk, Wkt, 4096, 1024);
  transpose_cvt<<<dim3(32, 128), 256, 0, stream>>>(Wv, Wvt, 4096, 1024);
  transpose_cvt<<<dim3(128, 128), 256, 0, stream>>>(Wo, Wot, 4096, 4096);

  gemm_bt<<<dim3(32, 32), 256, 0, stream>>>(Xq, Wqt, Qtmp, 4096, 4096, 4096);
  gemm_bt<<<dim3(8, 32), 256, 0, stream>>>(Xk, Wkt, Ktmp, 4096, 1024, 4096);
  gemm_bt<<<dim3(8, 32), 256, 0, stream>>>(Xv, Wvt, Vtmp, 4096, 1024, 4096);

  // Q pre-scaled by log2(e)/sqrt(D) so softmax runs in base-2 domain
  rope_cvt<<<(B_ * H_ * S_ * 64) / 256, 256, 0, stream>>>(Qtmp, Qr, pos, H_, 0.12751743f);
  rope_cvt<<<(B_ * KVH_ * S_ * 64) / 256, 256, 0, stream>>>(Ktmp, Kr, pos, KVH_, 1.0f);
  transpose_v<<<dim3(4, 64, 16), 256, 0, stream>>>(Vtmp, Vt);

  flash_attn<<<dim3(16, 32, 2), 256, 0, stream>>>(Qr, Kr, Vt, X);

  gemm_bt<<<dim3(32, 32), 256, 0, stream>>>(X, Wot, out, 4096, 4096, 4096);
}

// Round 3
// 1238.485 us; speedup vs baseline: 1.3074x; 1.3074x over previous
//
#include <hip/hip_runtime.h>
#include <stdint.h>

#define B_ 2
#define S_ 2048
#define E_ 4096
#define H_ 32
#define KVH_ 8
#define D_ 128

typedef __bf16 bf16_t;
typedef __bf16 bf16x8 __attribute__((ext_vector_type(8)));
typedef __bf16 bf16x4 __attribute__((ext_vector_type(4)));
typedef float f32x4 __attribute__((ext_vector_type(4)));

// global -> LDS direct copy, 16B per lane. LDS dest = wave-uniform base + lane*16.
__device__ __forceinline__ void gl2lds16(const void* g, void* l) {
  __builtin_amdgcn_global_load_lds(
      (__attribute__((address_space(1))) void*)(uintptr_t)g,
      (__attribute__((address_space(3))) void*)(uint32_t)(uintptr_t)l,
      16, 0, 0);
}

// ---------------- elementwise fp32 -> bf16 ----------------
__global__ void cvt_f32_bf16(const float* __restrict__ in, bf16_t* __restrict__ out, int n4) {
  int i = blockIdx.x * 256 + threadIdx.x;
  if (i < n4) {
    float4 v = ((const float4*)in)[i];
    bf16x4 o;
    o.x = (bf16_t)v.x; o.y = (bf16_t)v.y; o.z = (bf16_t)v.z; o.w = (bf16_t)v.w;
    ((bf16x4*)out)[i] = o;
  }
}

// ---------------- transpose + convert: in (R,C) fp32 -> out (C,R) bf16 ----------------
__global__ void transpose_cvt(const float* __restrict__ in, bf16_t* __restrict__ out,
                              int R, int C) {
  __shared__ float t[32][33];
  int r0 = blockIdx.y * 32, c0 = blockIdx.x * 32;
  int tx = threadIdx.x & 31, tg = threadIdx.x >> 5;
#pragma unroll
  for (int k = 0; k < 4; ++k) {
    int r = tg * 4 + k;
    t[r][tx] = in[(long)(r0 + r) * C + c0 + tx];
  }
  __syncthreads();
#pragma unroll
  for (int k = 0; k < 4; ++k) {
    int r = tg * 4 + k;
    out[(long)(c0 + r) * R + r0 + tx] = (bf16_t)t[tx][r];
  }
}

// ---------------- V: (B*S, KVH*D) fp32 -> (B,KVH,D,S) bf16 ----------------
__global__ void transpose_v(const float* __restrict__ Vtmp, bf16_t* __restrict__ Vt) {
  __shared__ float t[32][33];
  int z = blockIdx.z, b = z >> 3, kv = z & 7;
  const float* in = Vtmp + (long)b * S_ * (KVH_ * D_) + kv * D_;
  bf16_t* out = Vt + ((long)(b * KVH_ + kv)) * D_ * S_;
  int s0 = blockIdx.y * 32, d0 = blockIdx.x * 32;
  int tx = threadIdx.x & 31, tg = threadIdx.x >> 5;
#pragma unroll
  for (int k = 0; k < 4; ++k) {
    int r = tg * 4 + k;
    t[r][tx] = in[(long)(s0 + r) * (KVH_ * D_) + d0 + tx];
  }
  __syncthreads();
#pragma unroll
  for (int k = 0; k < 4; ++k) {
    int r = tg * 4 + k;
    out[(long)(d0 + r) * S_ + s0 + tx] = (bf16_t)t[tx][r];
  }
}

// ---------------- RoPE + layout: (B*S, NH*D) fp32 -> (B,NH,S,D) bf16, * scale ----------------
__global__ void rope_cvt(const float* __restrict__ T, bf16_t* __restrict__ out,
                         const int* __restrict__ pos, int NH, float scale) {
  long idx = (long)blockIdx.x * 256 + threadIdx.x;  // B*NH*S*64 total
  int j = (int)(idx & 63);
  long t = idx >> 6;
  int s = (int)(t % S_); t /= S_;
  int nh = (int)(t % NH);
  int b = (int)(t / NH);
  long row = ((long)b * S_ + s) * ((long)NH * D_) + (long)nh * D_;
  float x1 = T[row + j];
  float x2 = T[row + j + 64];
  float p = (float)pos[(long)b * S_ + s];
  float inv = expf(-(float)j * (9.210340371976184f / 64.0f));  // 10000^(-j/64)
  float fr = p * inv;
  float c = cosf(fr), sn = sinf(fr);
  long ob = (((long)b * NH + nh) * S_ + s) * D_;
  out[ob + j]      = (bf16_t)((x1 * c - x2 * sn) * scale);
  out[ob + j + 64] = (bf16_t)((x2 * c + x1 * sn) * scale);
}

// ---------------- GEMM: C(M,N) fp32 = A(M,K) bf16 * Bt(N,K)^T bf16 ----------------
// m97 structure + XOR-swizzled LDS (granule g -> g ^ (row&7), 16B granules, 8/row).
__global__ __launch_bounds__(256, 2) void gemm_bt(
    const bf16_t* __restrict__ A, const bf16_t* __restrict__ Bt,
    float* __restrict__ C, int M, int N, int K) {
  __shared__ bf16_t As[128 * 64];
  __shared__ bf16_t Bs[128 * 64];
  const int tid = threadIdx.x;
  const int lane = tid & 63;
  const int wave = tid >> 6;
  const int m0 = blockIdx.y * 128, n0 = blockIdx.x * 128;
  const int wm = (wave >> 1) * 64, wn = (wave & 1) * 64;
  const int ln = lane & 15, quad = lane >> 4;
  const int srow = lane >> 3;          // row within 8-row chunk
  const int sg = lane & 7;             // granule slot within row

  f32x4 acc[4][4] = {};

  for (int kb = 0; kb < K; kb += 64) {
    __syncthreads();
#pragma unroll
    for (int it = 0; it < 4; ++it) {
      int c = wave * 4 + it;
      int row = c * 8 + srow;
      int g = sg ^ (row & 7);          // source granule for swizzled slot sg
      gl2lds16(A + (long)(m0 + row) * K + kb + g * 8, &As[c * 512 + lane * 8]);
      gl2lds16(Bt + (long)(n0 + row) * K + kb + g * 8, &Bs[c * 512 + lane * 8]);
    }
    __syncthreads();
#pragma unroll
    for (int ks = 0; ks < 2; ++ks) {
      bf16x8 af[4], bfr[4];
      const int go = ((ks * 4 + quad) ^ (ln & 7)) * 8;
#pragma unroll
      for (int i = 0; i < 4; ++i)
        af[i] = *(const bf16x8*)&As[(wm + i * 16 + ln) * 64 + go];
#pragma unroll
      for (int j = 0; j < 4; ++j)
        bfr[j] = *(const bf16x8*)&Bs[(wn + j * 16 + ln) * 64 + go];
#pragma unroll
      for (int i = 0; i < 4; ++i)
#pragma unroll
        for (int j = 0; j < 4; ++j)
          acc[i][j] = __builtin_amdgcn_mfma_f32_16x16x32_bf16(af[i], bfr[j], acc[i][j], 0, 0, 0);
    }
  }
#pragma unroll
  for (int i = 0; i < 4; ++i)
#pragma unroll
    for (int j = 0; j < 4; ++j)
#pragma unroll
      for (int r = 0; r < 4; ++r) {
        int m = m0 + wm + i * 16 + quad * 4 + r;
        int n = n0 + wn + j * 16 + ln;
        C[(long)m * N + n] = acc[i][j][r];
      }
}

// ---------------- causal GQA flash attention ----------------
// Q (B,H,S,D) bf16 PRE-SCALED by log2(e)/sqrt(D), Kr (B,KVH,S,D), Vt (B,KVH,D,S)
// -> X (B*S, H*D) bf16.  LDS: Ks (aliased with per-wave P) + Vs = 64 KB.
// NOTE: __launch_bounds__(256,1): (256,2) caps VGPR at 128 -> massive scratch
// spills (R2: FETCH 434MB, WRITE 220MB, dur 740us). Unconstrained alloc lands
// ~164 VGPR which still fits 2 blocks/CU (2 waves/SIMD x 164 <= 512, LDS 64KB).
// All LDS tiles XOR-swizzled: 16 granules of 16B per 256B row, slot = g ^ (row&15).
__global__ __launch_bounds__(256, 1) void flash_attn(
    const bf16_t* __restrict__ Q, const bf16_t* __restrict__ Kr,
    const bf16_t* __restrict__ Vt, bf16_t* __restrict__ X) {
  __shared__ bf16_t Ks[128 * 128];   // QK operand; per-wave P quadrant after barrier C
  __shared__ bf16_t Vs[128 * 128];
  const int tid = threadIdx.x, lane = tid & 63, wave = tid >> 6;
  const int ln = lane & 15, quad = lane >> 4;
  const int qi = (int)(gridDim.x - 1 - blockIdx.x);  // heavy blocks dispatch first
  const int h = blockIdx.y, b = blockIdx.z;
  const int kv = h >> 2;  // GROUPS = 4
  const bf16_t* Kbase = Kr + (((long)b * KVH_ + kv) * S_) * D_;
  const bf16_t* Vbase = Vt + (((long)b * KVH_ + kv) * D_) * S_;
  bf16_t* Pw = &Ks[wave * 4096];     // this wave's 32x128 P tile (rows wave*32..)

  // Q fragments in registers (A-operand layout), Q already scaled
  bf16x8 aq[2][4];
  {
    const bf16_t* Qw = Q + (((long)b * H_ + h) * S_ + qi * 128 + wave * 32) * D_;
#pragma unroll
    for (int i = 0; i < 2; ++i)
#pragma unroll
      for (int ks = 0; ks < 4; ++ks)
        aq[i][ks] = *(const bf16x8*)(Qw + (i * 16 + ln) * D_ + ks * 32 + quad * 8);
  }

  f32x4 o_acc[2][8] = {};
  float m_cur[2][4], l_cur[2][4];
#pragma unroll
  for (int i = 0; i < 2; ++i)
#pragma unroll
    for (int r = 0; r < 4; ++r) { m_cur[i][r] = -__builtin_inff(); l_cur[i][r] = 0.f; }

  for (int jt = 0; jt <= qi; ++jt) {
    __syncthreads();  // (A) prior iter's P/Vs reads done before restaging
    const bf16_t* Kt = Kbase + (long)jt * 128 * D_;
#pragma unroll
    for (int it = 0; it < 8; ++it) {
      int c = wave * 8 + it;
      int row = c * 4 + quad;                 // LDS row (4 rows / 1KB chunk)
      int g = ln ^ (row & 15);                // source granule for slot ln
      gl2lds16(Kt + (long)row * D_ + g * 8, &Ks[c * 512 + lane * 8]);
      gl2lds16(Vbase + (long)row * S_ + jt * 128 + g * 8, &Vs[c * 512 + lane * 8]);
    }
    __syncthreads();  // (B) staging visible

    // S = Q K^T (base-2 log domain; Q pre-scaled)
    f32x4 s_acc[2][8] = {};
#pragma unroll
    for (int ks = 0; ks < 4; ++ks) {
      bf16x8 bk[8];
      const int go = ((ks * 4 + quad) ^ ln) * 8;
#pragma unroll
      for (int j = 0; j < 8; ++j)
        bk[j] = *(const bf16x8*)&Ks[(j * 16 + ln) * 128 + go];
#pragma unroll
      for (int i = 0; i < 2; ++i)
#pragma unroll
        for (int j = 0; j < 8; ++j)
          s_acc[i][j] = __builtin_amdgcn_mfma_f32_16x16x32_bf16(aq[i][ks], bk[j], s_acc[i][j], 0, 0, 0);
    }
    __syncthreads();  // (C) all waves done reading Ks -> safe to write P over it

#pragma unroll
    for (int i = 0; i < 2; ++i) {
      float rmax[4];
#pragma unroll
      for (int r = 0; r < 4; ++r) rmax[r] = -__builtin_inff();
#pragma unroll
      for (int j = 0; j < 8; ++j)
#pragma unroll
        for (int r = 0; r < 4; ++r) {
          float v = s_acc[i][j][r];
          if (jt == qi) {
            int qrow = wave * 32 + i * 16 + quad * 4 + r;
            int kcol = j * 16 + ln;
            if (kcol > qrow) v = -__builtin_inff();
          }
          s_acc[i][j][r] = v;
          rmax[r] = fmaxf(rmax[r], v);
        }
#pragma unroll
      for (int r = 0; r < 4; ++r) {
        float v = rmax[r];
        v = fmaxf(v, __shfl_xor(v, 1));
        v = fmaxf(v, __shfl_xor(v, 2));
        v = fmaxf(v, __shfl_xor(v, 4));
        v = fmaxf(v, __shfl_xor(v, 8));
        rmax[r] = v;
      }
      float alpha[4];
#pragma unroll
      for (int r = 0; r < 4; ++r) {
        float mn = fmaxf(m_cur[i][r], rmax[r]);
        alpha[r] = exp2f(m_cur[i][r] - mn);
        m_cur[i][r] = mn;
      }
      float rsum[4] = {0.f, 0.f, 0.f, 0.f};
#pragma unroll
      for (int j = 0; j < 8; ++j)
#pragma unroll
        for (int r = 0; r < 4; ++r) {
          float p = exp2f(s_acc[i][j][r] - m_cur[i][r]);
          s_acc[i][j][r] = p;
          rsum[r] += p;
        }
#pragma unroll
      for (int r = 0; r < 4; ++r) {
        float v = rsum[r];
        v += __shfl_xor(v, 1);
        v += __shfl_xor(v, 2);
        v += __shfl_xor(v, 4);
        v += __shfl_xor(v, 8);
        l_cur[i][r] = l_cur[i][r] * alpha[r] + v;
      }
#pragma unroll
      for (int j = 0; j < 8; ++j)
#pragma unroll
        for (int r = 0; r < 4; ++r)
          o_acc[i][j][r] *= alpha[r];
      // P -> wave-local LDS quadrant (swizzled), C-layout -> row-major 32x128
#pragma unroll
      for (int j = 0; j < 8; ++j)
#pragma unroll
        for (int r = 0; r < 4; ++r) {
          int prow = i * 16 + quad * 4 + r;
          int pg = (j * 2 + (ln >> 3)) ^ (prow & 15);
          Pw[prow * 128 + pg * 8 + (ln & 7)] = (bf16_t)s_acc[i][j][r];
        }
    }

    // O += P * V
#pragma unroll
    for (int ks = 0; ks < 4; ++ks) {
      bf16x8 ap[2], bv[8];
      const int go = ((ks * 4 + quad) ^ ln) * 8;
#pragma unroll
      for (int i = 0; i < 2; ++i)
        ap[i] = *(const bf16x8*)&Pw[(i * 16 + ln) * 128 + go];
#pragma unroll
      for (int j = 0; j < 8; ++j)
        bv[j] = *(const bf16x8*)&Vs[(j * 16 + ln) * 128 + go];
#pragma unroll
      for (int i = 0; i < 2; ++i)
#pragma unroll
        for (int j = 0; j < 8; ++j)
          o_acc[i][j] = __builtin_amdgcn_mfma_f32_16x16x32_bf16(ap[i], bv[j], o_acc[i][j], 0, 0, 0);
    }
  }

  // epilogue: X[b*S+q][h*D+d] = O / l
#pragma unroll
  for (int i = 0; i < 2; ++i) {
    float rl[4];
#pragma unroll
    for (int r = 0; r < 4; ++r) rl[r] = 1.0f / l_cur[i][r];
#pragma unroll
    for (int j = 0; j < 8; ++j)
#pragma unroll
      for (int r = 0; r < 4; ++r) {
        int q = qi * 128 + wave * 32 + i * 16 + quad * 4 + r;
        int dcol = j * 16 + ln;
        float o = o_acc[i][j][r] * rl[r];
        X[((long)b * S_ + q) * (H_ * D_) + (long)h * D_ + dcol] = (bf16_t)o;
      }
  }
}

extern "C" void kernel_launch(void* const* d_in, const int* in_sizes, int n_in,
                              void* d_out, int out_size, void* d_ws, size_t ws_size,
                              hipStream_t stream) {
  const float* query = (const float*)d_in[0];
  const float* key   = (const float*)d_in[1];
  const float* value = (const float*)d_in[2];
  const int*   pos   = (const int*)d_in[3];
  // d_in[4] = src_mask: deterministic causal tril -> handled analytically
  const float* Wq = (const float*)d_in[5];
  const float* Wk = (const float*)d_in[6];
  const float* Wv = (const float*)d_in[7];
  const float* Wo = (const float*)d_in[8];
  float* out = (float*)d_out;

  char* ws = (char*)d_ws;
  size_t off = 0;
  auto alloc = [&](size_t bytes) {
    char* p = ws + off;
    off += (bytes + 1023) & ~(size_t)1023;
    return p;
  };
  bf16_t* Wqt = (bf16_t*)alloc(33554432);  // (H*D, E) bf16
  bf16_t* Wkt = (bf16_t*)alloc(8388608);   // (KVH*D, E)
  bf16_t* Wvt = (bf16_t*)alloc(8388608);
  bf16_t* Wot = (bf16_t*)alloc(33554432);  // (E, H*D)
  bf16_t* Xq  = (bf16_t*)alloc(33554432);  // query bf16
  bf16_t* Xk  = (bf16_t*)alloc(33554432);
  bf16_t* Xv  = (bf16_t*)alloc(33554432);
  float*  Ktmp = (float*)alloc(16777216);  // (B*S, KVH*D) fp32
  float*  Vtmp = (float*)alloc(16777216);
  float*  Qtmp = out;                      // reuse d_out as fp32 Q-proj scratch
  bf16_t* Qr = Xk;                         // (B,H,S,D)    — Xk dead after K proj
  bf16_t* Kr = Xv;                         // (B,KVH,S,D)  — Xv dead after V proj
  bf16_t* Vt = (bf16_t*)((char*)Xv + 8388608);  // (B,KVH,D,S)
  bf16_t* X  = Xq;                         // attn out — Xq dead after Q proj

  const int n4 = B_ * S_ * E_ / 4;
  cvt_f32_bf16<<<n4 / 256, 256, 0, stream>>>(query, Xq, n4);
  cvt_f32_bf16<<<n4 / 256, 256, 0, stream>>>(key, Xk, n4);
  cvt_f32_bf16<<<n4 / 256, 256, 0, stream>>>(value, Xv, n4);

  transpose_cvt<<<dim3(128, 128), 256, 0, stream>>>(Wq, Wqt, 4096, 4096);
  transpose_cvt<<<dim3(32, 128), 256, 0, stream>>>(Wk, Wkt, 4096, 1024);
  transpose_cvt<<<dim3(32, 128), 256, 0, stream>>>(Wv, Wvt, 4096, 1024);
  transpose_cvt<<<dim3(128, 128), 256, 0, stream>>>(Wo, Wot, 4096, 4096);

  gemm_bt<<<dim3(32, 32), 256, 0, stream>>>(Xq, Wqt, Qtmp, 4096, 4096, 4096);
  gemm_bt<<<dim3(8, 32), 256, 0, stream>>>(Xk, Wkt, Ktmp, 4096, 1024, 4096);
  gemm_bt<<<dim3(8, 32), 256, 0, stream>>>(Xv, Wvt, Vtmp, 4096, 1024, 4096);

  // Q pre-scaled by log2(e)/sqrt(D) so softmax runs in base-2 domain
  rope_cvt<<<(B_ * H_ * S_ * 64) / 256, 256, 0, stream>>>(Qtmp, Qr, pos, H_, 0.12751743f);
  rope_cvt<<<(B_ * KVH_ * S_ * 64) / 256, 256, 0, stream>>>(Ktmp, Kr, pos, KVH_, 1.0f);
  transpose_v<<<dim3(4, 64, 16), 256, 0, stream>>>(Vtmp, Vt);

  flash_attn<<<dim3(16, 32, 2), 256, 0, stream>>>(Qr, Kr, Vt, X);

  gemm_bt<<<dim3(32, 32), 256, 0, stream>>>(X, Wot, out, 4096, 4096, 4096);
}